// Round 4
// baseline (158.013 us; speedup 1.0000x reference)
//
#include <hip/hip_runtime.h>
#include <stdint.h>

// ---- problem constants (PointRCNN RPN, KITTI Car) ----
#define BN 4
#define NPTS 16384
#define REGC 76
#define PRE 2250
#define PRE_PAD 2304          // 18*128, padded stride
#define POST 128
#define NBINS 4096            // 12-bit histogram on flipped float key
#define SORTN 4096            // candidate-set capacity
#define ECAP 4096             // max suppression edges per image
#define NMS_T 0.8f
#define TI 18                 // ceil(PRE/128)
#define NTRI 171              // TI*(TI+1)/2 upper-triangle tiles per image
#define SZB (BN * PRE_PAD)    // per-array stride for BEV SoA

// Order-preserving float->uint flip: ascending uint == ascending float.
__device__ __forceinline__ uint32_t flip_f32(float f) {
  uint32_t u = __float_as_uint(f);
  return (u & 0x80000000u) ? ~u : (u | 0x80000000u);
}
__device__ __forceinline__ float unflip_f32(uint32_t k) {
  uint32_t u = (k & 0x80000000u) ? (k & 0x7FFFFFFFu) : ~k;
  return __uint_as_float(u);
}

// Kernel 1 (FUSED hist + rank + decode), one block per image.
// Rationale: selkeys is only 32 KB/image. Keeping it in LDS removes the
// cross-kernel global round-trip (writes on one XCD's L2, reads missing to
// L3 at ~450cy from the other 7 XCDs made the rank scan latency-bound:
// 465-key threshold bin * ~268cy = the old 52us; batched global was ~22us).
// LDS scan: broadcast-friendly ds_read_b64 ~6cy -> worst thread ~2us.
// Also kills one launch + the binpack/selkeys/sel_cnt global arrays.
__global__ __launch_bounds__(1024) void k_histrank(
    const float* __restrict__ scores, const float* __restrict__ reg,
    const float* __restrict__ xyz, const float* __restrict__ anchor,
    float* __restrict__ ws_score, float* __restrict__ ws_pr,
    float* __restrict__ bev, int* __restrict__ edge_cnt) {
  __shared__ uint32_t hist[NBINS];          // counts, then base offsets (16 KB)
  __shared__ uint32_t ofs[NBINS];           // within-bin cursors -> counts (16 KB)
  __shared__ unsigned long long skey[SORTN];// candidate keys, bin-grouped (32 KB)
  __shared__ uint32_t wsum[16];
  __shared__ int s_bt, s_cnt;
  const int img = blockIdx.x, tid = threadIdx.x;
  const int wave = tid >> 6, lane = tid & 63;
  const float* sc = scores + img * NPTS;

  for (int i = tid; i < NBINS; i += 1024) { hist[i] = 0u; ofs[i] = 0u; }
  if (tid == 0) edge_cnt[img] = 0;
  __syncthreads();

  uint32_t k0[16];
#pragma unroll
  for (int r = 0; r < 16; ++r) {
    k0[r] = flip_f32(sc[tid + r * 1024]);
    atomicAdd(&hist[k0[r] >> 20], 1u);
  }
  __syncthreads();

  // suffix counts: thread owns 4 contiguous bins [4t, 4t+3]
  const uint32_t c0 = hist[4 * tid + 0], c1 = hist[4 * tid + 1];
  const uint32_t c2 = hist[4 * tid + 2], c3 = hist[4 * tid + 3];
  uint32_t s3 = c3, s2 = c2 + s3, s1 = c1 + s2, s0 = c0 + s1;
  const uint32_t tot = s0;
  uint32_t run = tot;  // inclusive suffix scan across wave (right-to-left)
#pragma unroll
  for (int off = 1; off < 64; off <<= 1) {
    uint32_t v = __shfl_down(run, off);
    if (lane + off < 64) run += v;
  }
  if (lane == 0) wsum[wave] = run;
  __syncthreads();
  uint32_t tail = 0;
  for (int w = wave + 1; w < 16; ++w) tail += wsum[w];
  const uint32_t after = run - tot + tail;  // suffix strictly after my bins
  const uint32_t S0 = s0 + after, S1 = s1 + after, S2 = s2 + after,
                 S3 = s3 + after;
  const uint32_t P = PRE;
  if (S0 >= P && S1 < P) { s_bt = 4 * tid + 0; s_cnt = (int)S0; }
  if (S1 >= P && S2 < P) { s_bt = 4 * tid + 1; s_cnt = (int)S1; }
  if (S2 >= P && S3 < P) { s_bt = 4 * tid + 2; s_cnt = (int)S2; }
  if (S3 >= P && after < P) { s_bt = 4 * tid + 3; s_cnt = (int)S3; }

  // overwrite hist with per-bin base offsets: base(b) = suffix(b+1)
  hist[4 * tid + 0] = S1;
  hist[4 * tid + 1] = S2;
  hist[4 * tid + 2] = S3;
  hist[4 * tid + 3] = after;
  __syncthreads();
  const int bt = s_bt;

  // compact candidates (bin >= bt) into LDS, grouped by bin
#pragma unroll
  for (int r = 0; r < 16; ++r) {
    const int bin = (int)(k0[r] >> 20);
    if (bin >= bt) {
      uint32_t pos = hist[bin] + atomicAdd(&ofs[bin], 1u);
      if (pos < SORTN)
        skey[pos] =
            ((unsigned long long)(~k0[r]) << 32) | (uint32_t)(tid + r * 1024);
    }
  }
  __syncthreads();
  // after compact: hist[bin] = base, ofs[bin] = true bin count

  const int cnt = s_cnt < SORTN ? s_cnt : SORTN;
  for (int i = tid; i < cnt; i += 1024) {
    const unsigned long long myk = skey[i];
    const uint32_t flip = ~(uint32_t)(myk >> 32);
    const int bin = (int)(flip >> 20);
    const int base = (int)hist[bin];
    int end = base + (int)ofs[bin];
    end = end < SORTN ? end : SORTN;

    int rank = base;
    for (int q = base; q < end; ++q) rank += (int)(skey[q] < myk);
    if (rank >= PRE) continue;

    const int r = rank;
    const int idx = (int)(uint32_t)myk;
    ws_score[img * PRE_PAD + r] = unflip_f32(~(uint32_t)(myk >> 32));

    const float* rr = reg + (size_t)(img * NPTS + idx) * REGC;
    float v[REGC];
    const float4* r4 = reinterpret_cast<const float4*>(rr);
#pragma unroll
    for (int qq = 0; qq < REGC / 4; ++qq) {
      float4 f = r4[qq];
      v[4 * qq + 0] = f.x; v[4 * qq + 1] = f.y;
      v[4 * qq + 2] = f.z; v[4 * qq + 3] = f.w;
    }

    // first-occurrence argmax (strict >) matches jnp.argmax
    int xb = 0; float xm = v[0];
#pragma unroll
    for (int c = 1; c < 12; ++c) if (v[c] > xm) { xm = v[c]; xb = c; }
    int zb = 0; float zm = v[12];
#pragma unroll
    for (int c = 1; c < 12; ++c) if (v[12 + c] > zm) { zm = v[12 + c]; zb = c; }
    float xres = v[24];
#pragma unroll
    for (int c = 1; c < 12; ++c) if (xb == c) xres = v[24 + c];
    float zres = v[36];
#pragma unroll
    for (int c = 1; c < 12; ++c) if (zb == c) zres = v[36 + c];

    float posx = xb * 0.5f + 0.25f - 3.0f + xres * 0.5f;
    float posz = zb * 0.5f + 0.25f - 3.0f + zres * 0.5f;

    const float* xp = xyz + (size_t)(img * NPTS + idx) * 3;
    float X = posx + xp[0];
    float Y = xp[1] + v[48];
    float Z = posz + xp[2];

    int ryb = 0; float rym = v[49];
#pragma unroll
    for (int c = 1; c < 12; ++c) if (v[49 + c] > rym) { rym = v[49 + c]; ryb = c; }
    float ryres = v[61];
#pragma unroll
    for (int c = 1; c < 12; ++c) if (ryb == c) ryres = v[61 + c];

    const float APC = 0.5235987755982988f;    // (f32)(2pi/12)
    const float APC2 = 0.2617993877991494f;   // (f32)(pi/12)
    const float TWO_PI_F = 6.283185307179586f;
    const float PI_F = 3.141592653589793f;
    float ry = ryb * APC + ryres * APC2;
    ry = fmodf(ry, TWO_PI_F);
    if (ry < 0.0f) ry += TWO_PI_F;            // floored mod, matches np/jnp %
    if (ry > PI_F) ry -= TWO_PI_F;

    float ah = anchor[0], aw = anchor[1], al = anchor[2];
    float H = v[73] * ah + ah;
    float W = v[74] * aw + aw;
    float L = v[75] * al + al;
    Y += H * 0.5f;                            // y += h/2

    float* pr = ws_pr + (size_t)(img * PRE_PAD + r) * 7;
    pr[0] = X; pr[1] = Y; pr[2] = Z; pr[3] = H; pr[4] = W; pr[5] = L; pr[6] = ry;

    int o = img * PRE_PAD + r;
    float x1 = X - L * 0.5f, x2 = X + L * 0.5f;
    float z1 = Z - W * 0.5f, z2 = Z + W * 0.5f;
    bev[o] = x1;
    bev[SZB + o] = x2;
    bev[2 * SZB + o] = z1;
    bev[3 * SZB + o] = z2;
    bev[4 * SZB + o] = (x2 - x1) * (z2 - z1);
  }
}

// Kernel 2: all-pairs (i<j) IoU > 0.8 -> sparse edge list per image.
// LDS staging; column box in registers, row reads are LDS broadcasts.
__global__ __launch_bounds__(256) void k_pairs(
    const float* __restrict__ bev, uint32_t* __restrict__ edges,
    int* __restrict__ edge_cnt) {
  int bx = blockIdx.x;
  int img = bx / NTRI;
  int t = bx - img * NTRI;
  int ti = 0, acc = 0;
#pragma unroll
  for (int row = 0; row < TI; ++row) {
    int c = TI - row;
    if (t < acc + c) { ti = row; break; }
    acc += c;
  }
  int tj = ti + (t - acc);

  __shared__ float rx1[128], rx2[128], rz1[128], rz2[128], ra[128];
  __shared__ float cx1[128], cx2[128], cz1[128], cz2[128], ca[128];
  int tid = threadIdx.x;
  if (tid < 128) {
    int o = img * PRE_PAD + ti * 128 + tid;
    rx1[tid] = bev[o];           rx2[tid] = bev[SZB + o];
    rz1[tid] = bev[2 * SZB + o]; rz2[tid] = bev[3 * SZB + o];
    ra[tid] = bev[4 * SZB + o];
  } else {
    int q = tid - 128;
    int o = img * PRE_PAD + tj * 128 + q;
    cx1[q] = bev[o];             cx2[q] = bev[SZB + o];
    cz1[q] = bev[2 * SZB + o];   cz2[q] = bev[3 * SZB + o];
    ca[q] = bev[4 * SZB + o];
  }
  __syncthreads();

  const int b = tid & 127;
  const int a0 = tid >> 7;
  const float bx1 = cx1[b], bx2 = cx2[b], bz1 = cz1[b], bz2 = cz2[b],
              bar = ca[b];
  const int j = tj * 128 + b;
  for (int a = a0; a < 128; a += 2) {
    int i = ti * 128 + a;
    if (i < j && j < PRE) {
      float iw = fminf(rx2[a], bx2) - fmaxf(rx1[a], bx1);
      iw = fmaxf(iw, 0.0f);
      float ih = fminf(rz2[a], bz2) - fmaxf(rz1[a], bz1);
      ih = fmaxf(ih, 0.0f);
      float inter = iw * ih;
      float iou = inter / (ra[a] + bar - inter);  // true IEEE div, ref-exact
      if (iou > NMS_T) {
        int e = atomicAdd(&edge_cnt[img], 1);
        if (e < ECAP) edges[img * ECAP + e] = ((uint32_t)i << 16) | (uint32_t)j;
      }
    }
  }
}

// Kernel 3: greedy-NMS resolve. Bitonic sort of edges now BLOCK-WIDE (all
// 16 waves, __syncthreads between passes; previously wave-0-only left 15/16
// waves idle). Then single-thread greedy walk (source-sorted => sup[si]
// final when visited), keep-flag ranks via shfl wave-scan, emit POST.
__global__ __launch_bounds__(1024) void k_resolve(
    const uint32_t* __restrict__ edges, const int* __restrict__ edge_cnt,
    const float* __restrict__ ws_pr, const float* __restrict__ ws_score,
    float* __restrict__ out) {
  __shared__ uint32_t sup[PRE];     // 9 KB
  __shared__ uint32_t earr[ECAP];   // 16 KB
  __shared__ uint32_t wtot[16];
  const int img = blockIdx.x, tid = threadIdx.x;
  const int wave = tid >> 6, lane = tid & 63;

  for (int i = tid; i < PRE; i += 1024) sup[i] = 0u;
  int E = edge_cnt[img];
  E = E < 0 ? 0 : (E > ECAP ? ECAP : E);
  int P2 = 1;
  while (P2 < E) P2 <<= 1;
  for (int e = tid; e < P2; e += 1024)
    earr[e] = (e < E) ? edges[img * ECAP + e] : 0xFFFFFFFFu;
  __syncthreads();

  // block-wide bitonic sort asc by (i<<16|j); trip counts uniform across
  // the block (P2 from a block-uniform load), so barriers are safe.
  for (int k = 2; k <= P2; k <<= 1)
    for (int j = k >> 1; j > 0; j >>= 1) {
      for (int t = tid; t < (P2 >> 1); t += 1024) {
        int ii = ((t & ~(j - 1)) << 1) | (t & (j - 1));
        int l = ii | j;
        uint32_t a = earr[ii], b = earr[l];
        if ((a > b) == ((ii & k) == 0)) { earr[ii] = b; earr[l] = a; }
      }
      __syncthreads();
    }

  if (tid == 0) {
    for (int e = 0; e < E; ++e) {
      uint32_t u = earr[e];
      uint32_t si = u >> 16, sj = u & 0xFFFFu;
      if (!sup[si]) sup[sj] = 1u;  // source-sorted => sup[si] final here
    }
  }
  __syncthreads();

  // ranks: 4 contiguous elements/thread, shfl inclusive scan across wave
  const int q0 = 4 * tid;
  uint32_t f0 = (q0 + 0 < PRE && !sup[q0 + 0]) ? 1u : 0u;
  uint32_t f1 = (q0 + 1 < PRE && !sup[q0 + 1]) ? 1u : 0u;
  uint32_t f2 = (q0 + 2 < PRE && !sup[q0 + 2]) ? 1u : 0u;
  uint32_t f3 = (q0 + 3 < PRE && !sup[q0 + 3]) ? 1u : 0u;
  uint32_t p0 = f0, p1 = p0 + f1, p2 = p1 + f2, p3 = p2 + f3;
  const uint32_t tot = p3;
  uint32_t run = tot;
#pragma unroll
  for (int off = 1; off < 64; off <<= 1) {
    uint32_t v = __shfl_up(run, off);
    if (lane >= off) run += v;
  }
  if (lane == 63) wtot[wave] = run;
  __syncthreads();
  uint32_t wbase = 0, total = 0;
  for (int w = 0; w < 16; ++w) {
    uint32_t t = wtot[w];
    if (w < wave) wbase += t;
    total += t;
  }
  const uint32_t before = wbase + run - tot;  // exclusive prefix at q0

  float* ob = out + (size_t)img * POST * 7;
  float* os = out + (size_t)(BN * POST * 7) + img * POST;
  uint32_t fc[4] = {f0, f1, f2, f3};
  uint32_t pc[4] = {p0, p1, p2, p3};
#pragma unroll
  for (int c = 0; c < 4; ++c) {
    if (fc[c]) {
      int rk = (int)(before + pc[c]) - 1;
      if (rk < POST) {
        const float* p = ws_pr + (size_t)(img * PRE_PAD + (q0 + c)) * 7;
#pragma unroll
        for (int cc = 0; cc < 7; ++cc) ob[rk * 7 + cc] = p[cc];
        os[rk] = ws_score[img * PRE_PAD + (q0 + c)];
      }
    }
  }
  for (int rk = (int)total + tid; rk < POST; rk += 1024) {
#pragma unroll
    for (int cc = 0; cc < 7; ++cc) ob[rk * 7 + cc] = 0.0f;
    os[rk] = 0.0f;
  }
}

extern "C" void kernel_launch(void* const* d_in, const int* in_sizes, int n_in,
                              void* d_out, int out_size, void* d_ws, size_t ws_size,
                              hipStream_t stream) {
  const float* scores = (const float*)d_in[0];
  const float* reg = (const float*)d_in[1];
  const float* xyz = (const float*)d_in[2];
  const float* anchor = (const float*)d_in[3];
  float* out = (float*)d_out;
  char* ws = (char*)d_ws;

  // workspace layout (bytes)
  uint32_t* edges = (uint32_t*)(ws + 0);         // BN*ECAP u32      = 65536
  float* ws_score = (float*)(ws + 65536);        // BN*PRE_PAD f32   = 36864
  float* ws_pr = (float*)(ws + 102400);          // BN*PRE_PAD*7 f32 = 258048
  float* bev = (float*)(ws + 360448);            // 5*SZB f32        = 184320
  int* edge_cnt = (int*)(ws + 544768);           // BN int

  k_histrank<<<BN, 1024, 0, stream>>>(scores, reg, xyz, anchor, ws_score,
                                      ws_pr, bev, edge_cnt);
  k_pairs<<<BN * NTRI, 256, 0, stream>>>(bev, edges, edge_cnt);
  k_resolve<<<BN, 1024, 0, stream>>>(edges, edge_cnt, ws_pr, ws_score, out);
}

// Round 5
// 151.541 us; speedup vs baseline: 1.0427x; 1.0427x over previous
//
#include <hip/hip_runtime.h>
#include <stdint.h>

// ---- problem constants (PointRCNN RPN, KITTI Car) ----
#define BN 4
#define NPTS 16384
#define REGC 76
#define PRE 2250
#define PRE_PAD 2304          // 18*128, padded stride
#define POST 128
#define NBINS 4096            // 12-bit histogram on flipped float key
#define SORTN 4096            // candidate-set capacity
#define ECAP 4096             // max suppression edges per image
#define NMS_T 0.8f
#define TI 18                 // ceil(PRE/128)
#define NTRI 171              // TI*(TI+1)/2 upper-triangle tiles per image
#define SZB (BN * PRE_PAD)    // per-array stride for BEV SoA
#define DECB 9                // decode blocks per image (9*256 = 2304 >= PRE)

// Order-preserving float->uint flip: ascending uint == ascending float.
__device__ __forceinline__ uint32_t flip_f32(float f) {
  uint32_t u = __float_as_uint(f);
  return (u & 0x80000000u) ? ~u : (u | 0x80000000u);
}
__device__ __forceinline__ float unflip_f32(uint32_t k) {
  uint32_t u = (k & 0x80000000u) ? (k & 0x7FFFFFFFu) : ~k;
  return __uint_as_float(u);
}

// Kernel 1: hist + compact + LDS rank, one block per image.
// Outputs the rank->point-index permutation (srt) + sorted scores ONLY.
// The heavy scattered reg-gather decode is NOT here: at 4 blocks this
// kernel owns 4 CUs, and round-4 showed a 4-CU scattered gather is
// latency-bound at ~35 GB/s (50+ us). Rank scan stays in LDS where the
// threshold bin's ~465-key segment reads are broadcast-friendly (~cheap).
__global__ __launch_bounds__(1024) void k_histrank(
    const float* __restrict__ scores, uint32_t* __restrict__ srt,
    float* __restrict__ ws_score, int* __restrict__ edge_cnt) {
  __shared__ uint32_t hist[NBINS];          // counts, then base offsets (16 KB)
  __shared__ uint32_t ofs[NBINS];           // within-bin cursors -> counts (16 KB)
  __shared__ unsigned long long skey[SORTN];// candidate keys, bin-grouped (32 KB)
  __shared__ uint32_t wsum[16];
  __shared__ int s_bt, s_cnt;
  const int img = blockIdx.x, tid = threadIdx.x;
  const int wave = tid >> 6, lane = tid & 63;
  const float* sc = scores + img * NPTS;

  for (int i = tid; i < NBINS; i += 1024) { hist[i] = 0u; ofs[i] = 0u; }
  if (tid == 0) edge_cnt[img] = 0;
  __syncthreads();

  uint32_t k0[16];
#pragma unroll
  for (int r = 0; r < 16; ++r) {
    k0[r] = flip_f32(sc[tid + r * 1024]);
    atomicAdd(&hist[k0[r] >> 20], 1u);
  }
  __syncthreads();

  // suffix counts: thread owns 4 contiguous bins [4t, 4t+3]
  const uint32_t c0 = hist[4 * tid + 0], c1 = hist[4 * tid + 1];
  const uint32_t c2 = hist[4 * tid + 2], c3 = hist[4 * tid + 3];
  uint32_t s3 = c3, s2 = c2 + s3, s1 = c1 + s2, s0 = c0 + s1;
  const uint32_t tot = s0;
  uint32_t run = tot;  // inclusive suffix scan across wave (right-to-left)
#pragma unroll
  for (int off = 1; off < 64; off <<= 1) {
    uint32_t v = __shfl_down(run, off);
    if (lane + off < 64) run += v;
  }
  if (lane == 0) wsum[wave] = run;
  __syncthreads();
  uint32_t tail = 0;
  for (int w = wave + 1; w < 16; ++w) tail += wsum[w];
  const uint32_t after = run - tot + tail;  // suffix strictly after my bins
  const uint32_t S0 = s0 + after, S1 = s1 + after, S2 = s2 + after,
                 S3 = s3 + after;
  const uint32_t P = PRE;
  if (S0 >= P && S1 < P) { s_bt = 4 * tid + 0; s_cnt = (int)S0; }
  if (S1 >= P && S2 < P) { s_bt = 4 * tid + 1; s_cnt = (int)S1; }
  if (S2 >= P && S3 < P) { s_bt = 4 * tid + 2; s_cnt = (int)S2; }
  if (S3 >= P && after < P) { s_bt = 4 * tid + 3; s_cnt = (int)S3; }

  // overwrite hist with per-bin base offsets: base(b) = suffix(b+1)
  hist[4 * tid + 0] = S1;
  hist[4 * tid + 1] = S2;
  hist[4 * tid + 2] = S3;
  hist[4 * tid + 3] = after;
  __syncthreads();
  const int bt = s_bt;

  // compact candidates (bin >= bt) into LDS, grouped by bin
#pragma unroll
  for (int r = 0; r < 16; ++r) {
    const int bin = (int)(k0[r] >> 20);
    if (bin >= bt) {
      uint32_t pos = hist[bin] + atomicAdd(&ofs[bin], 1u);
      if (pos < SORTN)
        skey[pos] =
            ((unsigned long long)(~k0[r]) << 32) | (uint32_t)(tid + r * 1024);
    }
  }
  __syncthreads();
  // after compact: hist[bin] = base, ofs[bin] = true bin count

  const int cnt = s_cnt < SORTN ? s_cnt : SORTN;
  for (int i = tid; i < cnt; i += 1024) {
    const unsigned long long myk = skey[i];
    const uint32_t flip = ~(uint32_t)(myk >> 32);
    const int bin = (int)(flip >> 20);
    const int base = (int)hist[bin];
    int end = base + (int)ofs[bin];
    end = end < SORTN ? end : SORTN;

    int rank = base;
    for (int q = base; q < end; ++q) rank += (int)(skey[q] < myk);
    if (rank >= PRE) continue;

    srt[img * PRE_PAD + rank] = (uint32_t)myk;  // point index, sorted order
    ws_score[img * PRE_PAD + rank] = unflip_f32(~(uint32_t)(myk >> 32));
  }
}

// Kernel 2: decode the PRE ranked candidates. 36 blocks -> the scattered
// 304 B/candidate reg gather gets full-device memory parallelism: one
// ~700cy round-trip of 19 independent float4 loads per thread.
__global__ __launch_bounds__(256) void k_dec(
    const uint32_t* __restrict__ srt, const float* __restrict__ reg,
    const float* __restrict__ xyz, const float* __restrict__ anchor,
    float* __restrict__ ws_pr, float* __restrict__ bev) {
  const int img = blockIdx.x / DECB;
  const int r = (blockIdx.x % DECB) * 256 + threadIdx.x;
  if (r >= PRE) return;
  const int idx = (int)srt[img * PRE_PAD + r];

  const float* rr = reg + (size_t)(img * NPTS + idx) * REGC;
  float v[REGC];
  const float4* r4 = reinterpret_cast<const float4*>(rr);
#pragma unroll
  for (int qq = 0; qq < REGC / 4; ++qq) {
    float4 f = r4[qq];
    v[4 * qq + 0] = f.x; v[4 * qq + 1] = f.y;
    v[4 * qq + 2] = f.z; v[4 * qq + 3] = f.w;
  }

  // first-occurrence argmax (strict >) matches jnp.argmax
  int xb = 0; float xm = v[0];
#pragma unroll
  for (int c = 1; c < 12; ++c) if (v[c] > xm) { xm = v[c]; xb = c; }
  int zb = 0; float zm = v[12];
#pragma unroll
  for (int c = 1; c < 12; ++c) if (v[12 + c] > zm) { zm = v[12 + c]; zb = c; }
  float xres = v[24];
#pragma unroll
  for (int c = 1; c < 12; ++c) if (xb == c) xres = v[24 + c];
  float zres = v[36];
#pragma unroll
  for (int c = 1; c < 12; ++c) if (zb == c) zres = v[36 + c];

  float posx = xb * 0.5f + 0.25f - 3.0f + xres * 0.5f;
  float posz = zb * 0.5f + 0.25f - 3.0f + zres * 0.5f;

  const float* xp = xyz + (size_t)(img * NPTS + idx) * 3;
  float X = posx + xp[0];
  float Y = xp[1] + v[48];
  float Z = posz + xp[2];

  int ryb = 0; float rym = v[49];
#pragma unroll
  for (int c = 1; c < 12; ++c) if (v[49 + c] > rym) { rym = v[49 + c]; ryb = c; }
  float ryres = v[61];
#pragma unroll
  for (int c = 1; c < 12; ++c) if (ryb == c) ryres = v[61 + c];

  const float APC = 0.5235987755982988f;    // (f32)(2pi/12)
  const float APC2 = 0.2617993877991494f;   // (f32)(pi/12)
  const float TWO_PI_F = 6.283185307179586f;
  const float PI_F = 3.141592653589793f;
  float ry = ryb * APC + ryres * APC2;
  ry = fmodf(ry, TWO_PI_F);
  if (ry < 0.0f) ry += TWO_PI_F;            // floored mod, matches np/jnp %
  if (ry > PI_F) ry -= TWO_PI_F;

  float ah = anchor[0], aw = anchor[1], al = anchor[2];
  float H = v[73] * ah + ah;
  float W = v[74] * aw + aw;
  float L = v[75] * al + al;
  Y += H * 0.5f;                            // y += h/2

  float* pr = ws_pr + (size_t)(img * PRE_PAD + r) * 7;
  pr[0] = X; pr[1] = Y; pr[2] = Z; pr[3] = H; pr[4] = W; pr[5] = L; pr[6] = ry;

  int o = img * PRE_PAD + r;
  float x1 = X - L * 0.5f, x2 = X + L * 0.5f;
  float z1 = Z - W * 0.5f, z2 = Z + W * 0.5f;
  bev[o] = x1;
  bev[SZB + o] = x2;
  bev[2 * SZB + o] = z1;
  bev[3 * SZB + o] = z2;
  bev[4 * SZB + o] = (x2 - x1) * (z2 - z1);
}

// Kernel 3: all-pairs (i<j) IoU > 0.8 -> sparse edge list per image.
// LDS staging; column box in registers, row reads are LDS broadcasts.
__global__ __launch_bounds__(256) void k_pairs(
    const float* __restrict__ bev, uint32_t* __restrict__ edges,
    int* __restrict__ edge_cnt) {
  int bx = blockIdx.x;
  int img = bx / NTRI;
  int t = bx - img * NTRI;
  int ti = 0, acc = 0;
#pragma unroll
  for (int row = 0; row < TI; ++row) {
    int c = TI - row;
    if (t < acc + c) { ti = row; break; }
    acc += c;
  }
  int tj = ti + (t - acc);

  __shared__ float rx1[128], rx2[128], rz1[128], rz2[128], ra[128];
  __shared__ float cx1[128], cx2[128], cz1[128], cz2[128], ca[128];
  int tid = threadIdx.x;
  if (tid < 128) {
    int o = img * PRE_PAD + ti * 128 + tid;
    rx1[tid] = bev[o];           rx2[tid] = bev[SZB + o];
    rz1[tid] = bev[2 * SZB + o]; rz2[tid] = bev[3 * SZB + o];
    ra[tid] = bev[4 * SZB + o];
  } else {
    int q = tid - 128;
    int o = img * PRE_PAD + tj * 128 + q;
    cx1[q] = bev[o];             cx2[q] = bev[SZB + o];
    cz1[q] = bev[2 * SZB + o];   cz2[q] = bev[3 * SZB + o];
    ca[q] = bev[4 * SZB + o];
  }
  __syncthreads();

  const int b = tid & 127;
  const int a0 = tid >> 7;
  const float bx1 = cx1[b], bx2 = cx2[b], bz1 = cz1[b], bz2 = cz2[b],
              bar = ca[b];
  const int j = tj * 128 + b;
  for (int a = a0; a < 128; a += 2) {
    int i = ti * 128 + a;
    if (i < j && j < PRE) {
      float iw = fminf(rx2[a], bx2) - fmaxf(rx1[a], bx1);
      iw = fmaxf(iw, 0.0f);
      float ih = fminf(rz2[a], bz2) - fmaxf(rz1[a], bz1);
      ih = fmaxf(ih, 0.0f);
      float inter = iw * ih;
      float iou = inter / (ra[a] + bar - inter);  // true IEEE div, ref-exact
      if (iou > NMS_T) {
        int e = atomicAdd(&edge_cnt[img], 1);
        if (e < ECAP) edges[img * ECAP + e] = ((uint32_t)i << 16) | (uint32_t)j;
      }
    }
  }
}

// Kernel 4: greedy-NMS resolve. Block-wide bitonic sort of edges, then a
// single-thread greedy walk (source-sorted => sup[si] final when visited).
// Walk caches sup[si] across runs of equal si (edges sorted => runs are
// contiguous), removing one dependent LDS read per edge within a run.
__global__ __launch_bounds__(1024) void k_resolve(
    const uint32_t* __restrict__ edges, const int* __restrict__ edge_cnt,
    const float* __restrict__ ws_pr, const float* __restrict__ ws_score,
    float* __restrict__ out) {
  __shared__ uint32_t sup[PRE];     // 9 KB
  __shared__ uint32_t earr[ECAP];   // 16 KB
  __shared__ uint32_t wtot[16];
  const int img = blockIdx.x, tid = threadIdx.x;
  const int wave = tid >> 6, lane = tid & 63;

  for (int i = tid; i < PRE; i += 1024) sup[i] = 0u;
  int E = edge_cnt[img];
  E = E < 0 ? 0 : (E > ECAP ? ECAP : E);
  int P2 = 1;
  while (P2 < E) P2 <<= 1;
  for (int e = tid; e < P2; e += 1024)
    earr[e] = (e < E) ? edges[img * ECAP + e] : 0xFFFFFFFFu;
  __syncthreads();

  // block-wide bitonic sort asc by (i<<16|j); trip counts uniform across
  // the block (P2 from a block-uniform load), so barriers are safe.
  for (int k = 2; k <= P2; k <<= 1)
    for (int j = k >> 1; j > 0; j >>= 1) {
      for (int t = tid; t < (P2 >> 1); t += 1024) {
        int ii = ((t & ~(j - 1)) << 1) | (t & (j - 1));
        int l = ii | j;
        uint32_t a = earr[ii], b = earr[l];
        if ((a > b) == ((ii & k) == 0)) { earr[ii] = b; earr[l] = a; }
      }
      __syncthreads();
    }

  if (tid == 0) {
    int lastsi = -1;
    uint32_t keep_si = 0u;
    for (int e = 0; e < E; ++e) {
      uint32_t u = earr[e];
      int si = (int)(u >> 16), sj = (int)(u & 0xFFFFu);
      if (si != lastsi) { lastsi = si; keep_si = !sup[si]; }
      if (keep_si) sup[sj] = 1u;  // source-sorted => sup[si] final here
    }
  }
  __syncthreads();

  // ranks: 4 contiguous elements/thread, shfl inclusive scan across wave
  const int q0 = 4 * tid;
  uint32_t f0 = (q0 + 0 < PRE && !sup[q0 + 0]) ? 1u : 0u;
  uint32_t f1 = (q0 + 1 < PRE && !sup[q0 + 1]) ? 1u : 0u;
  uint32_t f2 = (q0 + 2 < PRE && !sup[q0 + 2]) ? 1u : 0u;
  uint32_t f3 = (q0 + 3 < PRE && !sup[q0 + 3]) ? 1u : 0u;
  uint32_t p0 = f0, p1 = p0 + f1, p2 = p1 + f2, p3 = p2 + f3;
  const uint32_t tot = p3;
  uint32_t run = tot;
#pragma unroll
  for (int off = 1; off < 64; off <<= 1) {
    uint32_t v = __shfl_up(run, off);
    if (lane >= off) run += v;
  }
  if (lane == 63) wtot[wave] = run;
  __syncthreads();
  uint32_t wbase = 0, total = 0;
  for (int w = 0; w < 16; ++w) {
    uint32_t t = wtot[w];
    if (w < wave) wbase += t;
    total += t;
  }
  const uint32_t before = wbase + run - tot;  // exclusive prefix at q0

  float* ob = out + (size_t)img * POST * 7;
  float* os = out + (size_t)(BN * POST * 7) + img * POST;
  uint32_t fc[4] = {f0, f1, f2, f3};
  uint32_t pc[4] = {p0, p1, p2, p3};
#pragma unroll
  for (int c = 0; c < 4; ++c) {
    if (fc[c]) {
      int rk = (int)(before + pc[c]) - 1;
      if (rk < POST) {
        const float* p = ws_pr + (size_t)(img * PRE_PAD + (q0 + c)) * 7;
#pragma unroll
        for (int cc = 0; cc < 7; ++cc) ob[rk * 7 + cc] = p[cc];
        os[rk] = ws_score[img * PRE_PAD + (q0 + c)];
      }
    }
  }
  for (int rk = (int)total + tid; rk < POST; rk += 1024) {
#pragma unroll
    for (int cc = 0; cc < 7; ++cc) ob[rk * 7 + cc] = 0.0f;
    os[rk] = 0.0f;
  }
}

extern "C" void kernel_launch(void* const* d_in, const int* in_sizes, int n_in,
                              void* d_out, int out_size, void* d_ws, size_t ws_size,
                              hipStream_t stream) {
  const float* scores = (const float*)d_in[0];
  const float* reg = (const float*)d_in[1];
  const float* xyz = (const float*)d_in[2];
  const float* anchor = (const float*)d_in[3];
  float* out = (float*)d_out;
  char* ws = (char*)d_ws;

  // workspace layout (bytes)
  uint32_t* edges = (uint32_t*)(ws + 0);         // BN*ECAP u32      = 65536
  float* ws_score = (float*)(ws + 65536);        // BN*PRE_PAD f32   = 36864
  float* ws_pr = (float*)(ws + 102400);          // BN*PRE_PAD*7 f32 = 258048
  float* bev = (float*)(ws + 360448);            // 5*SZB f32        = 184320
  int* edge_cnt = (int*)(ws + 544768);           // BN int           = 16
  uint32_t* srt = (uint32_t*)(ws + 544800);      // BN*PRE_PAD u32   = 36864

  k_histrank<<<BN, 1024, 0, stream>>>(scores, srt, ws_score, edge_cnt);
  k_dec<<<BN * DECB, 256, 0, stream>>>(srt, reg, xyz, anchor, ws_pr, bev);
  k_pairs<<<BN * NTRI, 256, 0, stream>>>(bev, edges, edge_cnt);
  k_resolve<<<BN, 1024, 0, stream>>>(edges, edge_cnt, ws_pr, ws_score, out);
}

// Round 6
// 106.602 us; speedup vs baseline: 1.4823x; 1.4216x over previous
//
#include <hip/hip_runtime.h>
#include <stdint.h>

// ---- problem constants (PointRCNN RPN, KITTI Car) ----
#define BN 4
#define NPTS 16384
#define REGC 76
#define PRE 2250
#define PRE_PAD 2304          // 18*128, padded stride
#define POST 128
#define NBINS 4096            // 12-bit level-1 histogram on flipped float key
#define NB2 8192              // 13-bit level-2: 31 coarse x 256 fine + overflow
#define SORTN 4096            // candidate-set capacity
#define ECAP 4096             // max suppression edges per image
#define NMS_T 0.8f
#define TI 18                 // ceil(PRE/128)
#define NTRI 171              // TI*(TI+1)/2 upper-triangle tiles per image
#define SZB (BN * PRE_PAD)    // per-array stride for BEV SoA
#define DECB 9                // decode blocks per image (9*256 = 2304 >= PRE)

// Order-preserving float->uint flip: ascending uint == ascending float.
__device__ __forceinline__ uint32_t flip_f32(float f) {
  uint32_t u = __float_as_uint(f);
  return (u & 0x80000000u) ? ~u : (u | 0x80000000u);
}
__device__ __forceinline__ float unflip_f32(uint32_t k) {
  uint32_t u = (k & 0x80000000u) ? (k & 0x7FFFFFFFu) : ~k;
  return __uint_as_float(u);
}

// 13-bit fine key for candidates (bin >= bt). Order-preserving with score:
// larger key2 <=> strictly-not-lower score bucket. bins >= bt+31 collapse to
// a single overflow bin 8191 (score > ~4.9, expected ~0 keys) which is
// > all regular keys2; exact order inside any sub-bin is resolved by the
// full 64-bit compare in the segment scan.
__device__ __forceinline__ uint32_t fine_key(uint32_t flp, int bt) {
  const int d = (int)(flp >> 20) - bt;
  return (d >= 31) ? 8191u : (((uint32_t)d << 8) | ((flp >> 12) & 0xFFu));
}

// Kernel 1: hist + two-level rank, one block per image.
// Round-5 lesson: with only a 12-bit key, EVERY Gaussian-tail bin near the
// threshold holds hundreds of keys (495,435,380,...), so the within-bin
// rank scan costs Sum cnt^2 ~ 890K LDS reads on 4 CUs = 47us. Level-2
// re-histogram of the ~2400 candidates at 13-bit granularity drops sub-bin
// occupancy to ~1.8 -> ~6K scan reads.
__global__ __launch_bounds__(1024) void k_histrank(
    const float* __restrict__ scores, uint32_t* __restrict__ srt,
    float* __restrict__ ws_score, int* __restrict__ edge_cnt) {
  __shared__ uint32_t h2[NB2];              // lvl1 hist in [0,4096); lvl2 hist->base->end (32 KB)
  __shared__ uint32_t o2[NB2];              // lvl2 counts (32 KB)
  __shared__ unsigned long long skey[SORTN];// candidate keys, key2-grouped (32 KB)
  __shared__ uint32_t wsum[16];
  __shared__ int s_bt, s_cnt;
  const int img = blockIdx.x, tid = threadIdx.x;
  const int wave = tid >> 6, lane = tid & 63;
  const float* sc = scores + img * NPTS;

  for (int i = tid; i < NBINS; i += 1024) h2[i] = 0u;
  if (tid == 0) edge_cnt[img] = 0;
  __syncthreads();

  uint32_t k0[16];
#pragma unroll
  for (int r = 0; r < 16; ++r) {
    k0[r] = flip_f32(sc[tid + r * 1024]);
    atomicAdd(&h2[k0[r] >> 20], 1u);
  }
  __syncthreads();

  // level-1 suffix scan (4 bins/thread) -> threshold bin bt + cand count
  const uint32_t c0 = h2[4 * tid + 0], c1 = h2[4 * tid + 1];
  const uint32_t c2 = h2[4 * tid + 2], c3 = h2[4 * tid + 3];
  uint32_t s3 = c3, s2 = c2 + s3, s1 = c1 + s2, s0 = c0 + s1;
  const uint32_t tot = s0;
  uint32_t run = tot;  // inclusive suffix scan across wave
#pragma unroll
  for (int off = 1; off < 64; off <<= 1) {
    uint32_t v = __shfl_down(run, off);
    if (lane + off < 64) run += v;
  }
  if (lane == 0) wsum[wave] = run;
  __syncthreads();
  uint32_t tail = 0;
  for (int w = wave + 1; w < 16; ++w) tail += wsum[w];
  const uint32_t after = run - tot + tail;  // suffix strictly after my bins
  const uint32_t S0 = s0 + after, S1 = s1 + after, S2 = s2 + after,
                 S3 = s3 + after;
  const uint32_t P = PRE;
  if (S0 >= P && S1 < P) { s_bt = 4 * tid + 0; s_cnt = (int)S0; }
  if (S1 >= P && S2 < P) { s_bt = 4 * tid + 1; s_cnt = (int)S1; }
  if (S2 >= P && S3 < P) { s_bt = 4 * tid + 2; s_cnt = (int)S2; }
  if (S3 >= P && after < P) { s_bt = 4 * tid + 3; s_cnt = (int)S3; }
  __syncthreads();
  const int bt = s_bt;

  // level-2: zero 8192 fine bins, histogram candidates only
  for (int i = tid; i < NB2; i += 1024) h2[i] = 0u;
  __syncthreads();
#pragma unroll
  for (int r = 0; r < 16; ++r) {
    if ((int)(k0[r] >> 20) >= bt) atomicAdd(&h2[fine_key(k0[r], bt)], 1u);
  }
  __syncthreads();

  // level-2 suffix scan (8 bins/thread): h2 -> base, o2 -> count
  uint32_t cc[8], ss[8];
#pragma unroll
  for (int j = 0; j < 8; ++j) cc[j] = h2[8 * tid + j];
  uint32_t acc2 = 0;
#pragma unroll
  for (int j = 7; j >= 0; --j) { acc2 += cc[j]; ss[j] = acc2; }
  const uint32_t tot2 = acc2;
  uint32_t run2 = tot2;
#pragma unroll
  for (int off = 1; off < 64; off <<= 1) {
    uint32_t v = __shfl_down(run2, off);
    if (lane + off < 64) run2 += v;
  }
  if (lane == 0) wsum[wave] = run2;
  __syncthreads();
  uint32_t tail2 = 0;
  for (int w = wave + 1; w < 16; ++w) tail2 += wsum[w];
  const uint32_t after2 = run2 - tot2 + tail2;
#pragma unroll
  for (int j = 0; j < 8; ++j) {
    o2[8 * tid + j] = cc[j];                             // count
    h2[8 * tid + j] = ((j < 7) ? ss[j + 1] : 0u) + after2;  // base = suffix(b+1)
  }
  __syncthreads();

  // compact candidates grouped by key2; h2 doubles as cursor (post: base+cnt)
#pragma unroll
  for (int r = 0; r < 16; ++r) {
    if ((int)(k0[r] >> 20) >= bt) {
      uint32_t pos = atomicAdd(&h2[fine_key(k0[r], bt)], 1u);
      if (pos < SORTN)
        skey[pos] =
            ((unsigned long long)(~k0[r]) << 32) | (uint32_t)(tid + r * 1024);
    }
  }
  __syncthreads();

  // rank = base + within-sub-bin rank (avg segment ~1.8, full-key compare)
  const int cnt = s_cnt < SORTN ? s_cnt : SORTN;
  for (int i = tid; i < cnt; i += 1024) {
    const unsigned long long myk = skey[i];
    const uint32_t flp = ~(uint32_t)(myk >> 32);
    const uint32_t key2 = fine_key(flp, bt);
    const int base2 = (int)h2[key2] - (int)o2[key2];
    int end = (int)h2[key2];
    end = end < SORTN ? end : SORTN;
    int rank = base2;
    for (int q = base2; q < end; ++q) rank += (int)(skey[q] < myk);
    if (rank >= PRE) continue;
    srt[img * PRE_PAD + rank] = (uint32_t)myk;  // point index, sorted order
    ws_score[img * PRE_PAD + rank] = unflip_f32(~(uint32_t)(myk >> 32));
  }
}

// Kernel 2: decode the PRE ranked candidates. 36 blocks -> the scattered
// 304 B/candidate reg gather gets full-device memory parallelism: one
// ~700cy round-trip of 19 independent float4 loads per thread.
__global__ __launch_bounds__(256) void k_dec(
    const uint32_t* __restrict__ srt, const float* __restrict__ reg,
    const float* __restrict__ xyz, const float* __restrict__ anchor,
    float* __restrict__ ws_pr, float* __restrict__ bev) {
  const int img = blockIdx.x / DECB;
  const int r = (blockIdx.x % DECB) * 256 + threadIdx.x;
  if (r >= PRE) return;
  const int idx = (int)srt[img * PRE_PAD + r];

  const float* rr = reg + (size_t)(img * NPTS + idx) * REGC;
  float v[REGC];
  const float4* r4 = reinterpret_cast<const float4*>(rr);
#pragma unroll
  for (int qq = 0; qq < REGC / 4; ++qq) {
    float4 f = r4[qq];
    v[4 * qq + 0] = f.x; v[4 * qq + 1] = f.y;
    v[4 * qq + 2] = f.z; v[4 * qq + 3] = f.w;
  }

  // first-occurrence argmax (strict >) matches jnp.argmax
  int xb = 0; float xm = v[0];
#pragma unroll
  for (int c = 1; c < 12; ++c) if (v[c] > xm) { xm = v[c]; xb = c; }
  int zb = 0; float zm = v[12];
#pragma unroll
  for (int c = 1; c < 12; ++c) if (v[12 + c] > zm) { zm = v[12 + c]; zb = c; }
  float xres = v[24];
#pragma unroll
  for (int c = 1; c < 12; ++c) if (xb == c) xres = v[24 + c];
  float zres = v[36];
#pragma unroll
  for (int c = 1; c < 12; ++c) if (zb == c) zres = v[36 + c];

  float posx = xb * 0.5f + 0.25f - 3.0f + xres * 0.5f;
  float posz = zb * 0.5f + 0.25f - 3.0f + zres * 0.5f;

  const float* xp = xyz + (size_t)(img * NPTS + idx) * 3;
  float X = posx + xp[0];
  float Y = xp[1] + v[48];
  float Z = posz + xp[2];

  int ryb = 0; float rym = v[49];
#pragma unroll
  for (int c = 1; c < 12; ++c) if (v[49 + c] > rym) { rym = v[49 + c]; ryb = c; }
  float ryres = v[61];
#pragma unroll
  for (int c = 1; c < 12; ++c) if (ryb == c) ryres = v[61 + c];

  const float APC = 0.5235987755982988f;    // (f32)(2pi/12)
  const float APC2 = 0.2617993877991494f;   // (f32)(pi/12)
  const float TWO_PI_F = 6.283185307179586f;
  const float PI_F = 3.141592653589793f;
  float ry = ryb * APC + ryres * APC2;
  ry = fmodf(ry, TWO_PI_F);
  if (ry < 0.0f) ry += TWO_PI_F;            // floored mod, matches np/jnp %
  if (ry > PI_F) ry -= TWO_PI_F;

  float ah = anchor[0], aw = anchor[1], al = anchor[2];
  float H = v[73] * ah + ah;
  float W = v[74] * aw + aw;
  float L = v[75] * al + al;
  Y += H * 0.5f;                            // y += h/2

  float* pr = ws_pr + (size_t)(img * PRE_PAD + r) * 7;
  pr[0] = X; pr[1] = Y; pr[2] = Z; pr[3] = H; pr[4] = W; pr[5] = L; pr[6] = ry;

  int o = img * PRE_PAD + r;
  float x1 = X - L * 0.5f, x2 = X + L * 0.5f;
  float z1 = Z - W * 0.5f, z2 = Z + W * 0.5f;
  bev[o] = x1;
  bev[SZB + o] = x2;
  bev[2 * SZB + o] = z1;
  bev[3 * SZB + o] = z2;
  bev[4 * SZB + o] = (x2 - x1) * (z2 - z1);
}

// Kernel 3: all-pairs (i<j) IoU > 0.8 -> sparse edge list per image.
// LDS staging; column box in registers, row reads are LDS broadcasts.
__global__ __launch_bounds__(256) void k_pairs(
    const float* __restrict__ bev, uint32_t* __restrict__ edges,
    int* __restrict__ edge_cnt) {
  int bx = blockIdx.x;
  int img = bx / NTRI;
  int t = bx - img * NTRI;
  int ti = 0, acc = 0;
#pragma unroll
  for (int row = 0; row < TI; ++row) {
    int c = TI - row;
    if (t < acc + c) { ti = row; break; }
    acc += c;
  }
  int tj = ti + (t - acc);

  __shared__ float rx1[128], rx2[128], rz1[128], rz2[128], ra[128];
  __shared__ float cx1[128], cx2[128], cz1[128], cz2[128], ca[128];
  int tid = threadIdx.x;
  if (tid < 128) {
    int o = img * PRE_PAD + ti * 128 + tid;
    rx1[tid] = bev[o];           rx2[tid] = bev[SZB + o];
    rz1[tid] = bev[2 * SZB + o]; rz2[tid] = bev[3 * SZB + o];
    ra[tid] = bev[4 * SZB + o];
  } else {
    int q = tid - 128;
    int o = img * PRE_PAD + tj * 128 + q;
    cx1[q] = bev[o];             cx2[q] = bev[SZB + o];
    cz1[q] = bev[2 * SZB + o];   cz2[q] = bev[3 * SZB + o];
    ca[q] = bev[4 * SZB + o];
  }
  __syncthreads();

  const int b = tid & 127;
  const int a0 = tid >> 7;
  const float bx1 = cx1[b], bx2 = cx2[b], bz1 = cz1[b], bz2 = cz2[b],
              bar = ca[b];
  const int j = tj * 128 + b;
  for (int a = a0; a < 128; a += 2) {
    int i = ti * 128 + a;
    if (i < j && j < PRE) {
      float iw = fminf(rx2[a], bx2) - fmaxf(rx1[a], bx1);
      iw = fmaxf(iw, 0.0f);
      float ih = fminf(rz2[a], bz2) - fmaxf(rz1[a], bz1);
      ih = fmaxf(ih, 0.0f);
      float inter = iw * ih;
      float iou = inter / (ra[a] + bar - inter);  // true IEEE div, ref-exact
      if (iou > NMS_T) {
        int e = atomicAdd(&edge_cnt[img], 1);
        if (e < ECAP) edges[img * ECAP + e] = ((uint32_t)i << 16) | (uint32_t)j;
      }
    }
  }
}

// Kernel 4: greedy-NMS resolve. Block-wide bitonic sort of edges, then a
// single-thread greedy walk (source-sorted => sup[si] final when visited).
__global__ __launch_bounds__(1024) void k_resolve(
    const uint32_t* __restrict__ edges, const int* __restrict__ edge_cnt,
    const float* __restrict__ ws_pr, const float* __restrict__ ws_score,
    float* __restrict__ out) {
  __shared__ uint32_t sup[PRE];     // 9 KB
  __shared__ uint32_t earr[ECAP];   // 16 KB
  __shared__ uint32_t wtot[16];
  const int img = blockIdx.x, tid = threadIdx.x;
  const int wave = tid >> 6, lane = tid & 63;

  for (int i = tid; i < PRE; i += 1024) sup[i] = 0u;
  int E = edge_cnt[img];
  E = E < 0 ? 0 : (E > ECAP ? ECAP : E);
  int P2 = 1;
  while (P2 < E) P2 <<= 1;
  for (int e = tid; e < P2; e += 1024)
    earr[e] = (e < E) ? edges[img * ECAP + e] : 0xFFFFFFFFu;
  __syncthreads();

  // block-wide bitonic sort asc by (i<<16|j); trip counts uniform across
  // the block (P2 from a block-uniform load), so barriers are safe.
  for (int k = 2; k <= P2; k <<= 1)
    for (int j = k >> 1; j > 0; j >>= 1) {
      for (int t = tid; t < (P2 >> 1); t += 1024) {
        int ii = ((t & ~(j - 1)) << 1) | (t & (j - 1));
        int l = ii | j;
        uint32_t a = earr[ii], b = earr[l];
        if ((a > b) == ((ii & k) == 0)) { earr[ii] = b; earr[l] = a; }
      }
      __syncthreads();
    }

  if (tid == 0) {
    int lastsi = -1;
    uint32_t keep_si = 0u;
    for (int e = 0; e < E; ++e) {
      uint32_t u = earr[e];
      int si = (int)(u >> 16), sj = (int)(u & 0xFFFFu);
      if (si != lastsi) { lastsi = si; keep_si = !sup[si]; }
      if (keep_si) sup[sj] = 1u;  // source-sorted => sup[si] final here
    }
  }
  __syncthreads();

  // ranks: 4 contiguous elements/thread, shfl inclusive scan across wave
  const int q0 = 4 * tid;
  uint32_t f0 = (q0 + 0 < PRE && !sup[q0 + 0]) ? 1u : 0u;
  uint32_t f1 = (q0 + 1 < PRE && !sup[q0 + 1]) ? 1u : 0u;
  uint32_t f2 = (q0 + 2 < PRE && !sup[q0 + 2]) ? 1u : 0u;
  uint32_t f3 = (q0 + 3 < PRE && !sup[q0 + 3]) ? 1u : 0u;
  uint32_t p0 = f0, p1 = p0 + f1, p2 = p1 + f2, p3 = p2 + f3;
  const uint32_t tot = p3;
  uint32_t run = tot;
#pragma unroll
  for (int off = 1; off < 64; off <<= 1) {
    uint32_t v = __shfl_up(run, off);
    if (lane >= off) run += v;
  }
  if (lane == 63) wtot[wave] = run;
  __syncthreads();
  uint32_t wbase = 0, total = 0;
  for (int w = 0; w < 16; ++w) {
    uint32_t t = wtot[w];
    if (w < wave) wbase += t;
    total += t;
  }
  const uint32_t before = wbase + run - tot;  // exclusive prefix at q0

  float* ob = out + (size_t)img * POST * 7;
  float* os = out + (size_t)(BN * POST * 7) + img * POST;
  uint32_t fc[4] = {f0, f1, f2, f3};
  uint32_t pc[4] = {p0, p1, p2, p3};
#pragma unroll
  for (int c = 0; c < 4; ++c) {
    if (fc[c]) {
      int rk = (int)(before + pc[c]) - 1;
      if (rk < POST) {
        const float* p = ws_pr + (size_t)(img * PRE_PAD + (q0 + c)) * 7;
#pragma unroll
        for (int cc = 0; cc < 7; ++cc) ob[rk * 7 + cc] = p[cc];
        os[rk] = ws_score[img * PRE_PAD + (q0 + c)];
      }
    }
  }
  for (int rk = (int)total + tid; rk < POST; rk += 1024) {
#pragma unroll
    for (int cc = 0; cc < 7; ++cc) ob[rk * 7 + cc] = 0.0f;
    os[rk] = 0.0f;
  }
}

extern "C" void kernel_launch(void* const* d_in, const int* in_sizes, int n_in,
                              void* d_out, int out_size, void* d_ws, size_t ws_size,
                              hipStream_t stream) {
  const float* scores = (const float*)d_in[0];
  const float* reg = (const float*)d_in[1];
  const float* xyz = (const float*)d_in[2];
  const float* anchor = (const float*)d_in[3];
  float* out = (float*)d_out;
  char* ws = (char*)d_ws;

  // workspace layout (bytes)
  uint32_t* edges = (uint32_t*)(ws + 0);         // BN*ECAP u32      = 65536
  float* ws_score = (float*)(ws + 65536);        // BN*PRE_PAD f32   = 36864
  float* ws_pr = (float*)(ws + 102400);          // BN*PRE_PAD*7 f32 = 258048
  float* bev = (float*)(ws + 360448);            // 5*SZB f32        = 184320
  int* edge_cnt = (int*)(ws + 544768);           // BN int           = 16
  uint32_t* srt = (uint32_t*)(ws + 544800);      // BN*PRE_PAD u32   = 36864

  k_histrank<<<BN, 1024, 0, stream>>>(scores, srt, ws_score, edge_cnt);
  k_dec<<<BN * DECB, 256, 0, stream>>>(srt, reg, xyz, anchor, ws_pr, bev);
  k_pairs<<<BN * NTRI, 256, 0, stream>>>(bev, edges, edge_cnt);
  k_resolve<<<BN, 1024, 0, stream>>>(edges, edge_cnt, ws_pr, ws_score, out);
}